// Round 1
// baseline (518.949 us; speedup 1.0000x reference)
//
#include <hip/hip_runtime.h>

typedef __attribute__((ext_vector_type(8))) short short8;
typedef __attribute__((ext_vector_type(4))) float floatx4;
typedef __attribute__((ext_vector_type(16))) float floatx16;
typedef __attribute__((ext_vector_type(4))) int intx4;

#define NPIX 4096
#define CH 256

static __device__ __forceinline__ unsigned short f2bf(float f) {
  union { float f; unsigned int u; } v; v.f = f;
  unsigned int u = v.u;
  return (unsigned short)((u + 0x7FFFu + ((u >> 16) & 1u)) >> 16);
}

// pack bf16(a) | bf16(b)<<16 : 3 VALU ops (2 int-add round + 1 v_perm)
static __device__ __forceinline__ unsigned int pk2bf(float a, float b) {
  union { float f; unsigned int u; } x, y; x.f = a; y.f = b;
  return __builtin_amdgcn_perm(y.u + 0x8000u, x.u + 0x8000u, 0x07060302u);
}

typedef __attribute__((address_space(3))) unsigned int lds_uint;
typedef const __attribute__((address_space(1))) unsigned int glob_uint;
static __device__ __forceinline__ void gload16(const void* g, void* l) {
  __builtin_amdgcn_global_load_lds((glob_uint*)g, (lds_uint*)l, 16, 0, 0);
}

// ---------------- weights fp32 -> bf16 ----------------
__global__ void conv_weights_kernel(const float* __restrict__ wq, const float* __restrict__ wk,
                                    const float* __restrict__ wv, const float* __restrict__ wo,
                                    unsigned short* __restrict__ wqkv, unsigned short* __restrict__ wob) {
  int i = blockIdx.x * 256 + threadIdx.x;   // 0..65535
  wqkv[i]          = f2bf(wq[i]);
  wqkv[65536 + i]  = f2bf(wk[i]);
  wqkv[131072 + i] = f2bf(wv[i]);
  wob[i]           = f2bf(wo[i]);
}

// ---------------- GroupNorm -> xnT bf16 [b][n][c] ----------------
__global__ __launch_bounds__(256) void gn_kernel(const float* __restrict__ x,
                                                 const float* __restrict__ gsc,
                                                 const float* __restrict__ gbi,
                                                 unsigned short* __restrict__ xnT) {
  int blk = blockIdx.x; int b = blk >> 5; int g = blk & 31;
  int c0 = g * 8;
  const float* xb = x + ((size_t)b * CH + c0) * NPIX;
  int tid = threadIdx.x;
  float s = 0.f, ss = 0.f;
#pragma unroll
  for (int ci = 0; ci < 8; ++ci) {
    const floatx4* p = (const floatx4*)(xb + (size_t)ci * NPIX);
    for (int n4 = tid; n4 < 1024; n4 += 256) {
      floatx4 v = p[n4];
      s += v[0] + v[1] + v[2] + v[3];
      ss += v[0]*v[0] + v[1]*v[1] + v[2]*v[2] + v[3]*v[3];
    }
  }
#pragma unroll
  for (int o = 32; o > 0; o >>= 1) { s += __shfl_down(s, o); ss += __shfl_down(ss, o); }
  __shared__ float red[10];
  int wid = tid >> 6;
  if ((tid & 63) == 0) { red[wid] = s; red[4 + wid] = ss; }
  __syncthreads();
  if (tid == 0) {
    float S = red[0] + red[1] + red[2] + red[3];
    float SS = red[4] + red[5] + red[6] + red[7];
    float mean = S * (1.f / 32768.f);
    float var = SS * (1.f / 32768.f) - mean * mean;
    red[8] = mean; red[9] = rsqrtf(var + 1e-5f);
  }
  __syncthreads();
  float mean = red[8], rstd = red[9];
  float sc[8], bi[8];
#pragma unroll
  for (int ci = 0; ci < 8; ++ci) {
    float scale = gsc[c0 + ci] * rstd;
    sc[ci] = scale;
    bi[ci] = gbi[c0 + ci] - mean * scale;
  }
  for (int n4 = tid; n4 < 1024; n4 += 256) {
    floatx4 v[8];
#pragma unroll
    for (int ci = 0; ci < 8; ++ci) v[ci] = ((const floatx4*)(xb + (size_t)ci * NPIX))[n4];
#pragma unroll
    for (int j = 0; j < 4; ++j) {
      alignas(16) unsigned short tmp[8];
#pragma unroll
      for (int ci = 0; ci < 8; ++ci) tmp[ci] = f2bf(v[ci][j] * sc[ci] + bi[ci]);
      *(intx4*)(xnT + ((size_t)(b * NPIX + n4 * 4 + j)) * CH + c0) = *(const intx4*)tmp;
    }
  }
}

// ---------------- QKV GEMM: D[o,n] = sum_c W[o,c]*xnT[n,c] + bias ----------------
// q pre-scaled by log2e/16 ; q,k written [n][o] bf16 ; v written [o][n] bf16
__global__ __launch_bounds__(256, 2) void qkv_gemm(
    const unsigned short* __restrict__ wqkv, const unsigned short* __restrict__ xnT,
    const float* __restrict__ bq, const float* __restrict__ bk, const float* __restrict__ bv,
    unsigned short* __restrict__ qT, unsigned short* __restrict__ kT, unsigned short* __restrict__ vC) {
  int nt = blockIdx.x, ot = blockIdx.y, bz = blockIdx.z;
  int which = bz % 3, b = bz / 3;
  const unsigned short* W = wqkv + which * 65536;
  const float* bias = which == 0 ? bq : (which == 1 ? bk : bv);
  const unsigned short* X = xnT + (size_t)b * NPIX * CH;
  int o0 = ot * 128, n0 = nt * 128;

  __shared__ unsigned short As[128 * 64];
  __shared__ unsigned short Bs[128 * 64];

  int tid = threadIdx.x;
  int wave = tid >> 6, lane = tid & 63, quad = lane >> 4, l16 = lane & 15;
  int wm = (wave >> 1) * 64, wn = (wave & 1) * 64;

  floatx4 acc[4][4];
#pragma unroll
  for (int i = 0; i < 4; ++i)
#pragma unroll
    for (int j = 0; j < 4; ++j) acc[i][j] = (floatx4){0.f, 0.f, 0.f, 0.f};

  for (int k0 = 0; k0 < 256; k0 += 64) {
    __syncthreads();
#pragma unroll
    for (int c2 = 0; c2 < 4; ++c2) {
      int row = wave * 32 + c2 * 8 + (lane >> 3);
      int sc = (lane & 7) ^ (row & 7);
      gload16(W + (size_t)(o0 + row) * CH + k0 + sc * 8, &As[(wave * 32 + c2 * 8) * 64]);
      gload16(X + (size_t)(n0 + row) * CH + k0 + sc * 8, &Bs[(wave * 32 + c2 * 8) * 64]);
    }
    __syncthreads();
#pragma unroll
    for (int s = 0; s < 2; ++s) {
      short8 af[4], bf[4];
#pragma unroll
      for (int i = 0; i < 4; ++i) {
        int m = wm + i * 16 + l16;
        af[i] = *(const short8*)(As + m * 64 + (((s * 4 + quad) ^ (m & 7)) * 8));
        int n = wn + i * 16 + l16;
        bf[i] = *(const short8*)(Bs + n * 64 + (((s * 4 + quad) ^ (n & 7)) * 8));
      }
#pragma unroll
      for (int i = 0; i < 4; ++i)
#pragma unroll
        for (int j = 0; j < 4; ++j)
          acc[i][j] = __builtin_amdgcn_mfma_f32_16x16x32_bf16(af[i], bf[j], acc[i][j], 0, 0, 0);
    }
  }

  if (which < 2) {
    // 0.0625 * log2(e)
    float qs = (which == 0) ? 0.090168440f : 1.0f;
    unsigned short* outp = (which == 0 ? qT : kT) + (size_t)b * NPIX * CH;
#pragma unroll
    for (int i = 0; i < 4; ++i) {
      int obase = o0 + wm + i * 16 + quad * 4;
      float bias4[4];
#pragma unroll
      for (int r = 0; r < 4; ++r) bias4[r] = bias[obase + r];
#pragma unroll
      for (int j = 0; j < 4; ++j) {
        int n = n0 + wn + j * 16 + l16;
        uint2 pk;
        pk.x = pk2bf((acc[i][j][0] + bias4[0]) * qs, (acc[i][j][1] + bias4[1]) * qs);
        pk.y = pk2bf((acc[i][j][2] + bias4[2]) * qs, (acc[i][j][3] + bias4[3]) * qs);
        *(uint2*)(outp + (size_t)n * CH + obase) = pk;
      }
    }
  } else {
    unsigned short* outp = vC + (size_t)b * CH * NPIX;
#pragma unroll
    for (int i = 0; i < 4; ++i)
#pragma unroll
      for (int r = 0; r < 4; ++r) {
        int o = o0 + wm + i * 16 + quad * 4 + r;
        float bb = bias[o];
#pragma unroll
        for (int j = 0; j < 4; ++j) {
          int n = n0 + wn + j * 16 + l16;
          outp[(size_t)o * NPIX + n] = f2bf(acc[i][j][r] + bb);
        }
      }
  }
}

// ---------------- fused attention: 1 block/CU, 8 waves, q-tile 128, KTILE=128 ----------
// grid 256: b = bid&7 (XCD-pinned), qt = bid>>3. 32 iters, SINGLE-buffered K/V (160KB LDS)
// with cross-phase staging: V(kt) staged during phase1(kt), K(kt+1) during phase2(kt).
// Phase1 (S^T = K·Q^T): roles 4 m-slices x 2 q-pairs; each wave 32m x 64q (32 MFMA),
//   K fragment reused across 2 register-resident Q fragments -> 0.5 KB LDS / MFMA.
// Phase2 (O^T += V·P^T): roles 4 c-slices(64) x 2 q-halves(64); 32 MFMA / wave.
// exp2 (log2e folded into Q), no max-subtraction; P bf16 -> LDS [q][m] XOR-8 swizzle.
// 32x32x16 layouts: A[m=lane&31][k=(lane>>5)*8+j]; B[k][n=lane&31]; D col=lane&31,
// row=(r&3)+8*(r>>2)+4*(lane>>5).
__global__ __launch_bounds__(512, 2) void attn_kernel(
    const unsigned short* __restrict__ qT, const unsigned short* __restrict__ kT,
    const unsigned short* __restrict__ vC, unsigned short* __restrict__ aT) {
  __shared__ unsigned short Klds[128 * 256];   // 64KB [m][c], 16B-chunk XOR-8 swizzle
  __shared__ unsigned short Vlds[256 * 128];   // 64KB [c][m], 16B-chunk XOR-8 swizzle
  __shared__ unsigned short Plds[128 * 128];   // 32KB [q][m], 16B-chunk XOR-8 swizzle
  // total 160KB exactly; lred reuses Plds after the main loop.

  const int tid = threadIdx.x;
  const int w = tid >> 6, lane = tid & 63;
  const int l32 = lane & 31, h = lane >> 5;
  const int b = blockIdx.x & 7, qt = blockIdx.x >> 3;
  const int qbase = qt * 128;

  const unsigned short* Kb = kT + (size_t)b * NPIX * CH;
  const unsigned short* Vb = vC + (size_t)b * CH * NPIX;

  const int ms  = (w & 3) * 32;   // phase-1 m-slice base
  const int qp  = (w >> 2) * 64;  // q base (phase 1 q-pair == phase 2 q-half)
  const int csl = (w & 3) * 64;   // phase-2 c-slice base

  // Q fragments (B-operand): q = qbase+qp+sub*32+l32, k=c = ks*16 + h*8 + j
  short8 qf[2][16];
  {
    const unsigned short* qq = qT + ((size_t)(b * NPIX + qbase + qp + l32)) * CH + h * 8;
#pragma unroll
    for (int sub = 0; sub < 2; ++sub)
#pragma unroll
      for (int ks = 0; ks < 16; ++ks)
        qf[sub][ks] = *(const short8*)(qq + sub * 32 * CH + ks * 16);
  }

  floatx16 o00 = {}, o01 = {}, o10 = {}, o11 = {};  // [csub][qsub] D[c][q]
  float l0 = 0.f, l1 = 0.f;

  // K tile stage: 128 rows x 512B; per wave 16 rows (2 rows / gload16, lanes 0-31 row r,
  // lanes 32-63 row r+1); source chunk pre-swizzled so LDS[phys]=global[phys^(r&7)].
#define STAGE_K(KT)                                                              \
  {                                                                              \
    int m0_ = (KT) * 128;                                                        \
    _Pragma("unroll") for (int j = 0; j < 8; ++j) {                              \
      int r_ = w * 16 + j * 2 + h;                                               \
      gload16(Kb + (size_t)(m0_ + r_) * CH + ((l32 ^ (r_ & 7)) * 8),             \
              &Klds[(w * 16 + j * 2) * 256]);                                    \
    }                                                                            \
  }
  // V tile stage: 256 rows x 256B; per wave 32 rows (4 rows / gload16).
#define STAGE_V(KT)                                                              \
  {                                                                              \
    int m0_ = (KT) * 128;                                                        \
    _Pragma("unroll") for (int j = 0; j < 8; ++j) {                              \
      int c_ = w * 32 + j * 4 + (lane >> 4);                                     \
      gload16(Vb + (size_t)c_ * NPIX + m0_ + (((lane & 15) ^ (c_ & 7)) * 8),     \
              &Vlds[(w * 32 + j * 4) * 128]);                                    \
    }                                                                            \
  }

  STAGE_K(0);
  asm volatile("s_waitcnt vmcnt(0)\ns_barrier" ::: "memory");

  for (int kt = 0; kt < 32; ++kt) {
    STAGE_V(kt);   // V(kt) lands during phase 1 (V buffer free: consumed last iter)

    // ---- phase 1: S^T tiles D[m 32][q 64] ----
    floatx16 s0 = {}, s1 = {};
    {
      const unsigned short* kr = &Klds[(ms + l32) * 256];
      const int mx = (ms + l32) & 7;
#pragma unroll
      for (int ks = 0; ks < 16; ++ks) {
        short8 kf = *(const short8*)(kr + (((ks * 2 + h) ^ mx) * 8));
        s0 = __builtin_amdgcn_mfma_f32_32x32x16_bf16(kf, qf[0][ks], s0, 0, 0, 0);
        s1 = __builtin_amdgcn_mfma_f32_32x32x16_bf16(kf, qf[1][ks], s1, 0, 0, 0);
      }
    }
    // exp2 + l partial sums (both h-halves share q = l32; halves differ in m)
    float sum0 = 0.f, sum1 = 0.f;
#pragma unroll
    for (int r = 0; r < 16; ++r) {
      float p0 = exp2f(s0[r]); s0[r] = p0; sum0 += p0;
      float p1 = exp2f(s1[r]); s1[r] = p1; sum1 += p1;
    }
    sum0 += __shfl_xor(sum0, 32); sum1 += __shfl_xor(sum1, 32);
    l0 += sum0; l1 += sum1;

    // P -> LDS: lane holds (q, m = ms + 8t + 4h + i) for reg r = 4t+i
    {
      int q0 = qp + l32, q1 = qp + 32 + l32;
#pragma unroll
      for (int t = 0; t < 4; ++t) {
        int g_ = (w & 3) * 4 + t;   // global 16B chunk index within the 128-m row
        uint2 wv;
        wv.x = pk2bf(s0[4 * t], s0[4 * t + 1]);
        wv.y = pk2bf(s0[4 * t + 2], s0[4 * t + 3]);
        *(uint2*)((char*)Plds + q0 * 256 + ((g_ ^ (q0 & 7)) * 16) + h * 8) = wv;
        wv.x = pk2bf(s1[4 * t], s1[4 * t + 1]);
        wv.y = pk2bf(s1[4 * t + 2], s1[4 * t + 3]);
        *(uint2*)((char*)Plds + q1 * 256 + ((g_ ^ (q1 & 7)) * 16) + h * 8) = wv;
      }
    }
    // barrier: V(kt) landed (vmcnt) + P visible (lgkm); K(kt) fully consumed
    asm volatile("s_waitcnt vmcnt(0) lgkmcnt(0)\ns_barrier" ::: "memory");
    if (kt + 1 < 32) STAGE_K(kt + 1);   // K(kt+1) lands during phase 2

    // ---- phase 2: O^T += V P^T, wave tile D[c 64][q 64] ----
    {
      const int q0 = qp + l32, q1 = qp + 32 + l32;
      const int c0 = csl + l32, c1 = csl + 32 + l32;
      const char* Pb = (const char*)Plds;
      const char* Vl = (const char*)Vlds;
#pragma unroll
      for (int ks = 0; ks < 8; ++ks) {
        int sl = ks * 2 + h;
        short8 pf0 = *(const short8*)(Pb + q0 * 256 + ((sl ^ (q0 & 7)) * 16));
        short8 pf1 = *(const short8*)(Pb + q1 * 256 + ((sl ^ (q1 & 7)) * 16));
        short8 vf0 = *(const short8*)(Vl + c0 * 256 + ((sl ^ (c0 & 7)) * 16));
        short8 vf1 = *(const short8*)(Vl + c1 * 256 + ((sl ^ (c1 & 7)) * 16));
        o00 = __builtin_amdgcn_mfma_f32_32x32x16_bf16(vf0, pf0, o00, 0, 0, 0);
        o01 = __builtin_amdgcn_mfma_f32_32x32x16_bf16(vf0, pf1, o01, 0, 0, 0);
        o10 = __builtin_amdgcn_mfma_f32_32x32x16_bf16(vf1, pf0, o10, 0, 0, 0);
        o11 = __builtin_amdgcn_mfma_f32_32x32x16_bf16(vf1, pf1, o11, 0, 0, 0);
      }
    }
    // barrier: K(kt+1) landed; V(kt)/P(kt) fully consumed
    asm volatile("s_waitcnt vmcnt(0) lgkmcnt(0)\ns_barrier" ::: "memory");
  }
#undef STAGE_K
#undef STAGE_V

  // ---- l reconciliation across the 4 m-slice waves (Plds reused as float[q][4]) ----
  float* lred = (float*)Plds;
  if (lane < 32) {
    lred[(qp + l32) * 4 + (w & 3)] = l0;
    lred[(qp + 32 + l32) * 4 + (w & 3)] = l1;
  }
  __syncthreads();
  float inv0, inv1;
  {
    const float* lp0 = &lred[(qp + l32) * 4];
    inv0 = 1.f / (lp0[0] + lp0[1] + lp0[2] + lp0[3]);
    const float* lp1 = &lred[(qp + 32 + l32) * 4];
    inv1 = 1.f / (lp1[0] + lp1[1] + lp1[2] + lp1[3]);
  }

  // ---- store O^T -> aT[q][c] bf16 ----
  unsigned short* ab = aT + (size_t)b * NPIX * CH;
  const floatx16 oa[2][2] = {{o00, o01}, {o10, o11}};
#pragma unroll
  for (int csub = 0; csub < 2; ++csub)
#pragma unroll
    for (int qsub = 0; qsub < 2; ++qsub) {
      int qg = qbase + qp + qsub * 32 + l32;
      float iv = qsub ? inv1 : inv0;
#pragma unroll
      for (int t = 0; t < 4; ++t) {
        int c = csl + csub * 32 + 8 * t + 4 * h;
        uint2 wv;
        wv.x = pk2bf(oa[csub][qsub][4 * t] * iv, oa[csub][qsub][4 * t + 1] * iv);
        wv.y = pk2bf(oa[csub][qsub][4 * t + 2] * iv, oa[csub][qsub][4 * t + 3] * iv);
        *(uint2*)(ab + (size_t)qg * CH + c) = wv;
      }
    }
}

// ---------------- output projection + bias + residual ----------------
__global__ __launch_bounds__(256, 2) void out_gemm(
    const unsigned short* __restrict__ wob, const unsigned short* __restrict__ aT,
    const float* __restrict__ bo, const float* __restrict__ x, float* __restrict__ outp) {
  int nt = blockIdx.x, ot = blockIdx.y, b = blockIdx.z;
  const unsigned short* A = aT + (size_t)b * NPIX * CH;
  int o0 = ot * 128, n0 = nt * 128;

  __shared__ unsigned short As[128 * 64];
  __shared__ unsigned short Bs[128 * 64];

  int tid = threadIdx.x;
  int wave = tid >> 6, lane = tid & 63, quad = lane >> 4, l16 = lane & 15;
  int wm = (wave >> 1) * 64, wn = (wave & 1) * 64;

  floatx4 acc[4][4];
#pragma unroll
  for (int i = 0; i < 4; ++i)
#pragma unroll
    for (int j = 0; j < 4; ++j) acc[i][j] = (floatx4){0.f, 0.f, 0.f, 0.f};

  for (int k0 = 0; k0 < 256; k0 += 64) {
    __syncthreads();
#pragma unroll
    for (int c2 = 0; c2 < 4; ++c2) {
      int row = wave * 32 + c2 * 8 + (lane >> 3);
      int sc = (lane & 7) ^ (row & 7);
      gload16(wob + (size_t)(o0 + row) * CH + k0 + sc * 8, &As[(wave * 32 + c2 * 8) * 64]);
      gload16(A + (size_t)(n0 + row) * CH + k0 + sc * 8, &Bs[(wave * 32 + c2 * 8) * 64]);
    }
    __syncthreads();
#pragma unroll
    for (int s = 0; s < 2; ++s) {
      short8 af[4], bf[4];
#pragma unroll
      for (int i = 0; i < 4; ++i) {
        int m = wm + i * 16 + l16;
        af[i] = *(const short8*)(As + m * 64 + (((s * 4 + quad) ^ (m & 7)) * 8));
        int n = wn + i * 16 + l16;
        bf[i] = *(const short8*)(Bs + n * 64 + (((s * 4 + quad) ^ (n & 7)) * 8));
      }
#pragma unroll
      for (int i = 0; i < 4; ++i)
#pragma unroll
        for (int j = 0; j < 4; ++j)
          acc[i][j] = __builtin_amdgcn_mfma_f32_16x16x32_bf16(af[i], bf[j], acc[i][j], 0, 0, 0);
    }
  }

#pragma unroll
  for (int i = 0; i < 4; ++i)
#pragma unroll
    for (int r = 0; r < 4; ++r) {
      int o = o0 + wm + i * 16 + quad * 4 + r;
      float bb = bo[o];
#pragma unroll
      for (int j = 0; j < 4; ++j) {
        int n = n0 + wn + j * 16 + l16;
        size_t idx = ((size_t)b * CH + o) * NPIX + n;
        outp[idx] = x[idx] + bb + acc[i][j][r];
      }
    }
}

extern "C" void kernel_launch(void* const* d_in, const int* in_sizes, int n_in,
                              void* d_out, int out_size, void* d_ws, size_t ws_size,
                              hipStream_t stream) {
  const float* x   = (const float*)d_in[0];
  const float* gsc = (const float*)d_in[1];
  const float* gbi = (const float*)d_in[2];
  const float* wq  = (const float*)d_in[3];
  const float* bq  = (const float*)d_in[4];
  const float* wk  = (const float*)d_in[5];
  const float* bk  = (const float*)d_in[6];
  const float* wv  = (const float*)d_in[7];
  const float* bv  = (const float*)d_in[8];
  const float* wo  = (const float*)d_in[9];
  const float* bo  = (const float*)d_in[10];
  float* out = (float*)d_out;

  char* ws = (char*)d_ws;
  unsigned short* xnT  = (unsigned short*)(ws);              // 16 MB (dead after qkv)
  unsigned short* qT   = (unsigned short*)(ws + 16777216);   // 16 MB
  unsigned short* kT   = (unsigned short*)(ws + 33554432);   // 16 MB
  unsigned short* vC   = (unsigned short*)(ws + 50331648);   // 16 MB
  unsigned short* wqkv = (unsigned short*)(ws + 67108864);   // 384 KB
  unsigned short* wob  = (unsigned short*)(ws + 67502080);   // 128 KB
  unsigned short* aT   = (unsigned short*)(ws + 67633152);   // 16 MB

  conv_weights_kernel<<<256, 256, 0, stream>>>(wq, wk, wv, wo, wqkv, wob);
  gn_kernel<<<256, 256, 0, stream>>>(x, gsc, gbi, xnT);
  dim3 g1(32, 2, 24);
  qkv_gemm<<<g1, 256, 0, stream>>>(wqkv, xnT, bq, bk, bv, qT, kT, vC);
  attn_kernel<<<256, 512, 0, stream>>>(qT, kT, vC, aT);
  dim3 g3(32, 2, 8);
  out_gemm<<<g3, 256, 0, stream>>>(wob, aT, bo, x, out);
}

// Round 2
// 339.057 us; speedup vs baseline: 1.5306x; 1.5306x over previous
//
#include <hip/hip_runtime.h>

typedef __attribute__((ext_vector_type(8))) short short8;
typedef __attribute__((ext_vector_type(4))) float floatx4;
typedef __attribute__((ext_vector_type(16))) float floatx16;
typedef __attribute__((ext_vector_type(4))) int intx4;

#define NPIX 4096
#define CH 256

static __device__ __forceinline__ unsigned short f2bf(float f) {
  union { float f; unsigned int u; } v; v.f = f;
  unsigned int u = v.u;
  return (unsigned short)((u + 0x7FFFu + ((u >> 16) & 1u)) >> 16);
}

// pack bf16(a) | bf16(b)<<16 : 3 VALU ops (2 int-add round + 1 v_perm)
static __device__ __forceinline__ unsigned int pk2bf(float a, float b) {
  union { float f; unsigned int u; } x, y; x.f = a; y.f = b;
  return __builtin_amdgcn_perm(y.u + 0x8000u, x.u + 0x8000u, 0x07060302u);
}

typedef __attribute__((address_space(3))) unsigned int lds_uint;
typedef const __attribute__((address_space(1))) unsigned int glob_uint;
static __device__ __forceinline__ void gload16(const void* g, void* l) {
  __builtin_amdgcn_global_load_lds((glob_uint*)g, (lds_uint*)l, 16, 0, 0);
}

// ---------------- weights fp32 -> bf16 ----------------
__global__ void conv_weights_kernel(const float* __restrict__ wq, const float* __restrict__ wk,
                                    const float* __restrict__ wv, const float* __restrict__ wo,
                                    unsigned short* __restrict__ wqkv, unsigned short* __restrict__ wob) {
  int i = blockIdx.x * 256 + threadIdx.x;   // 0..65535
  wqkv[i]          = f2bf(wq[i]);
  wqkv[65536 + i]  = f2bf(wk[i]);
  wqkv[131072 + i] = f2bf(wv[i]);
  wob[i]           = f2bf(wo[i]);
}

// ---------------- GroupNorm -> xnT bf16 [b][n][c] ----------------
__global__ __launch_bounds__(256) void gn_kernel(const float* __restrict__ x,
                                                 const float* __restrict__ gsc,
                                                 const float* __restrict__ gbi,
                                                 unsigned short* __restrict__ xnT) {
  int blk = blockIdx.x; int b = blk >> 5; int g = blk & 31;
  int c0 = g * 8;
  const float* xb = x + ((size_t)b * CH + c0) * NPIX;
  int tid = threadIdx.x;
  float s = 0.f, ss = 0.f;
#pragma unroll
  for (int ci = 0; ci < 8; ++ci) {
    const floatx4* p = (const floatx4*)(xb + (size_t)ci * NPIX);
    for (int n4 = tid; n4 < 1024; n4 += 256) {
      floatx4 v = p[n4];
      s += v[0] + v[1] + v[2] + v[3];
      ss += v[0]*v[0] + v[1]*v[1] + v[2]*v[2] + v[3]*v[3];
    }
  }
#pragma unroll
  for (int o = 32; o > 0; o >>= 1) { s += __shfl_down(s, o); ss += __shfl_down(ss, o); }
  __shared__ float red[10];
  int wid = tid >> 6;
  if ((tid & 63) == 0) { red[wid] = s; red[4 + wid] = ss; }
  __syncthreads();
  if (tid == 0) {
    float S = red[0] + red[1] + red[2] + red[3];
    float SS = red[4] + red[5] + red[6] + red[7];
    float mean = S * (1.f / 32768.f);
    float var = SS * (1.f / 32768.f) - mean * mean;
    red[8] = mean; red[9] = rsqrtf(var + 1e-5f);
  }
  __syncthreads();
  float mean = red[8], rstd = red[9];
  float sc[8], bi[8];
#pragma unroll
  for (int ci = 0; ci < 8; ++ci) {
    float scale = gsc[c0 + ci] * rstd;
    sc[ci] = scale;
    bi[ci] = gbi[c0 + ci] - mean * scale;
  }
  for (int n4 = tid; n4 < 1024; n4 += 256) {
    floatx4 v[8];
#pragma unroll
    for (int ci = 0; ci < 8; ++ci) v[ci] = ((const floatx4*)(xb + (size_t)ci * NPIX))[n4];
#pragma unroll
    for (int j = 0; j < 4; ++j) {
      alignas(16) unsigned short tmp[8];
#pragma unroll
      for (int ci = 0; ci < 8; ++ci) tmp[ci] = f2bf(v[ci][j] * sc[ci] + bi[ci]);
      *(intx4*)(xnT + ((size_t)(b * NPIX + n4 * 4 + j)) * CH + c0) = *(const intx4*)tmp;
    }
  }
}

// ---------------- QKV GEMM: D[o,n] = sum_c W[o,c]*xnT[n,c] + bias ----------------
// q pre-scaled by log2e/16 ; q,k written [n][o] bf16 ; v written [o][n] bf16
__global__ __launch_bounds__(256, 2) void qkv_gemm(
    const unsigned short* __restrict__ wqkv, const unsigned short* __restrict__ xnT,
    const float* __restrict__ bq, const float* __restrict__ bk, const float* __restrict__ bv,
    unsigned short* __restrict__ qT, unsigned short* __restrict__ kT, unsigned short* __restrict__ vC) {
  int nt = blockIdx.x, ot = blockIdx.y, bz = blockIdx.z;
  int which = bz % 3, b = bz / 3;
  const unsigned short* W = wqkv + which * 65536;
  const float* bias = which == 0 ? bq : (which == 1 ? bk : bv);
  const unsigned short* X = xnT + (size_t)b * NPIX * CH;
  int o0 = ot * 128, n0 = nt * 128;

  __shared__ unsigned short As[128 * 64];
  __shared__ unsigned short Bs[128 * 64];

  int tid = threadIdx.x;
  int wave = tid >> 6, lane = tid & 63, quad = lane >> 4, l16 = lane & 15;
  int wm = (wave >> 1) * 64, wn = (wave & 1) * 64;

  floatx4 acc[4][4];
#pragma unroll
  for (int i = 0; i < 4; ++i)
#pragma unroll
    for (int j = 0; j < 4; ++j) acc[i][j] = (floatx4){0.f, 0.f, 0.f, 0.f};

  for (int k0 = 0; k0 < 256; k0 += 64) {
    __syncthreads();
#pragma unroll
    for (int c2 = 0; c2 < 4; ++c2) {
      int row = wave * 32 + c2 * 8 + (lane >> 3);
      int sc = (lane & 7) ^ (row & 7);
      gload16(W + (size_t)(o0 + row) * CH + k0 + sc * 8, &As[(wave * 32 + c2 * 8) * 64]);
      gload16(X + (size_t)(n0 + row) * CH + k0 + sc * 8, &Bs[(wave * 32 + c2 * 8) * 64]);
    }
    __syncthreads();
#pragma unroll
    for (int s = 0; s < 2; ++s) {
      short8 af[4], bf[4];
#pragma unroll
      for (int i = 0; i < 4; ++i) {
        int m = wm + i * 16 + l16;
        af[i] = *(const short8*)(As + m * 64 + (((s * 4 + quad) ^ (m & 7)) * 8));
        int n = wn + i * 16 + l16;
        bf[i] = *(const short8*)(Bs + n * 64 + (((s * 4 + quad) ^ (n & 7)) * 8));
      }
#pragma unroll
      for (int i = 0; i < 4; ++i)
#pragma unroll
        for (int j = 0; j < 4; ++j)
          acc[i][j] = __builtin_amdgcn_mfma_f32_16x16x32_bf16(af[i], bf[j], acc[i][j], 0, 0, 0);
    }
  }

  if (which < 2) {
    // 0.0625 * log2(e)
    float qs = (which == 0) ? 0.090168440f : 1.0f;
    unsigned short* outp = (which == 0 ? qT : kT) + (size_t)b * NPIX * CH;
#pragma unroll
    for (int i = 0; i < 4; ++i) {
      int obase = o0 + wm + i * 16 + quad * 4;
      float bias4[4];
#pragma unroll
      for (int r = 0; r < 4; ++r) bias4[r] = bias[obase + r];
#pragma unroll
      for (int j = 0; j < 4; ++j) {
        int n = n0 + wn + j * 16 + l16;
        uint2 pk;
        pk.x = pk2bf((acc[i][j][0] + bias4[0]) * qs, (acc[i][j][1] + bias4[1]) * qs);
        pk.y = pk2bf((acc[i][j][2] + bias4[2]) * qs, (acc[i][j][3] + bias4[3]) * qs);
        *(uint2*)(outp + (size_t)n * CH + obase) = pk;
      }
    }
  } else {
    unsigned short* outp = vC + (size_t)b * CH * NPIX;
#pragma unroll
    for (int i = 0; i < 4; ++i)
#pragma unroll
      for (int r = 0; r < 4; ++r) {
        int o = o0 + wm + i * 16 + quad * 4 + r;
        float bb = bias[o];
#pragma unroll
        for (int j = 0; j < 4; ++j) {
          int n = n0 + wn + j * 16 + l16;
          outp[(size_t)o * NPIX + n] = f2bf(acc[i][j][r] + bb);
        }
      }
  }
}

// ---------------- fused attention: 1 block/CU, 8 waves, q-tile 128, KTILE=128 ----------
// grid 256: b = bid&7 (XCD-pinned), qt = bid>>3. 32 iters, SINGLE-buffered K/V (160KB LDS)
// with cross-phase staging: V(kt) staged during phase1(kt), K(kt+1) during phase2(kt).
// Phase1 (S^T = K·Q^T): roles 2 m-pairs(64) x 4 q-slices(32); each wave 64m x 32q
//   (32 MFMA, qf[16]=64 VGPRs only -- config B, avoids the round-1 register spill).
// Phase2 (O^T += V·P^T): roles 4 c-slices(64) x 2 q-halves(64); 32 MFMA / wave.
// exp2 (log2e folded into Q), no max-subtraction; P bf16 -> LDS [q][m] XOR-8 swizzle.
// 32x32x16 layouts: A[m=lane&31][k=(lane>>5)*8+j]; B[k][n=lane&31]; D col=lane&31,
// row=(r&3)+8*(r>>2)+4*(lane>>5).
__global__ __launch_bounds__(512, 2) void attn_kernel(
    const unsigned short* __restrict__ qT, const unsigned short* __restrict__ kT,
    const unsigned short* __restrict__ vC, unsigned short* __restrict__ aT) {
  __shared__ unsigned short Klds[128 * 256];   // 64KB [m][c], 16B-chunk XOR-8 swizzle
  __shared__ unsigned short Vlds[256 * 128];   // 64KB [c][m], 16B-chunk XOR-8 swizzle
  __shared__ unsigned short Plds[128 * 128];   // 32KB [q][m], 16B-chunk XOR-8 swizzle
  // total 160KB exactly; lred reuses Plds after the main loop.

  const int tid = threadIdx.x;
  const int w = tid >> 6, lane = tid & 63;
  const int l32 = lane & 31, h = lane >> 5;
  const int b = blockIdx.x & 7, qt = blockIdx.x >> 3;
  const int qbase = qt * 128;

  const unsigned short* Kb = kT + (size_t)b * NPIX * CH;
  const unsigned short* Vb = vC + (size_t)b * CH * NPIX;

  const int mp  = (w & 1) * 64;   // phase-1 m-pair base (covers [mp, mp+64))
  const int qsl = (w >> 1) * 32;  // phase-1 q-slice
  const int csl = (w & 3) * 64;   // phase-2 c-slice base
  const int qp  = (w >> 2) * 64;  // phase-2 q-half

  // Q fragments (B-operand): q = qbase+qsl+l32, k=c = ks*16 + h*8 + j  (64 VGPRs)
  short8 qf[16];
  {
    const unsigned short* qq = qT + ((size_t)(b * NPIX + qbase + qsl + l32)) * CH + h * 8;
#pragma unroll
    for (int ks = 0; ks < 16; ++ks) qf[ks] = *(const short8*)(qq + ks * 16);
  }

  floatx16 o00 = {}, o01 = {}, o10 = {}, o11 = {};  // [csub][qsub] D[c][q]
  float l_acc = 0.f;

  // K tile stage: 128 rows x 512B; per wave 16 rows (2 rows / gload16, lanes 0-31 row r,
  // lanes 32-63 row r+1); source chunk pre-swizzled so LDS[phys]=global[phys^(r&7)].
#define STAGE_K(KT)                                                              \
  {                                                                              \
    int m0_ = (KT) * 128;                                                        \
    _Pragma("unroll") for (int j = 0; j < 8; ++j) {                              \
      int r_ = w * 16 + j * 2 + h;                                               \
      gload16(Kb + (size_t)(m0_ + r_) * CH + ((l32 ^ (r_ & 7)) * 8),             \
              &Klds[(w * 16 + j * 2) * 256]);                                    \
    }                                                                            \
  }
  // V tile stage: 256 rows x 256B; per wave 32 rows (4 rows / gload16).
#define STAGE_V(KT)                                                              \
  {                                                                              \
    int m0_ = (KT) * 128;                                                        \
    _Pragma("unroll") for (int j = 0; j < 8; ++j) {                              \
      int c_ = w * 32 + j * 4 + (lane >> 4);                                     \
      gload16(Vb + (size_t)c_ * NPIX + m0_ + (((lane & 15) ^ (c_ & 7)) * 8),     \
              &Vlds[(w * 32 + j * 4) * 128]);                                    \
    }                                                                            \
  }

  STAGE_K(0);
  asm volatile("s_waitcnt vmcnt(0)\ns_barrier" ::: "memory");

  for (int kt = 0; kt < 32; ++kt) {
    STAGE_V(kt);   // V(kt) lands during phase 1 (V buffer free: consumed last iter)

    // ---- phase 1: S^T tiles D[m 64][q 32] (two 32x32 m-subtiles, shared qf) ----
    floatx16 s0 = {}, s1 = {};
    {
      const unsigned short* kr0 = &Klds[(mp + l32) * 256];
      const unsigned short* kr1 = &Klds[(mp + 32 + l32) * 256];
      const int mx = l32 & 7;   // (mp + l32) & 7 == (mp + 32 + l32) & 7
#pragma unroll
      for (int ks = 0; ks < 16; ++ks) {
        int off = ((ks * 2 + h) ^ mx) * 8;
        short8 kf0 = *(const short8*)(kr0 + off);
        short8 kf1 = *(const short8*)(kr1 + off);
        s0 = __builtin_amdgcn_mfma_f32_32x32x16_bf16(kf0, qf[ks], s0, 0, 0, 0);
        s1 = __builtin_amdgcn_mfma_f32_32x32x16_bf16(kf1, qf[ks], s1, 0, 0, 0);
      }
    }
    // exp2 + l partial sum (both m-subtiles share q = l32; h-halves differ in m)
    float sum = 0.f;
#pragma unroll
    for (int r = 0; r < 16; ++r) {
      float p0 = exp2f(s0[r]); s0[r] = p0; sum += p0;
      float p1 = exp2f(s1[r]); s1[r] = p1; sum += p1;
    }
    sum += __shfl_xor(sum, 32);
    l_acc += sum;

    // P -> LDS: lane holds (q = qsl+l32, m = mp + sub*32 + 8t + 4h + i) for reg r = 4t+i
    {
      int qrow = qsl + l32;
      int qx = qrow & 7;
      char* Pq = (char*)Plds + qrow * 256 + h * 8;
      int g0 = (w & 1) * 8;   // global 16B chunk base within the 128-m row
#pragma unroll
      for (int t = 0; t < 4; ++t) {
        uint2 wv;
        wv.x = pk2bf(s0[4 * t], s0[4 * t + 1]);
        wv.y = pk2bf(s0[4 * t + 2], s0[4 * t + 3]);
        *(uint2*)(Pq + (((g0 + t) ^ qx) * 16)) = wv;
        wv.x = pk2bf(s1[4 * t], s1[4 * t + 1]);
        wv.y = pk2bf(s1[4 * t + 2], s1[4 * t + 3]);
        *(uint2*)(Pq + (((g0 + 4 + t) ^ qx) * 16)) = wv;
      }
    }
    // barrier: V(kt) landed (vmcnt) + P visible (lgkm); K(kt) fully consumed
    asm volatile("s_waitcnt vmcnt(0) lgkmcnt(0)\ns_barrier" ::: "memory");
    if (kt + 1 < 32) STAGE_K(kt + 1);   // K(kt+1) lands during phase 2

    // ---- phase 2: O^T += V P^T, wave tile D[c 64][q 64] ----
    {
      const int q0 = qp + l32, q1 = qp + 32 + l32;
      const int c0 = csl + l32, c1 = csl + 32 + l32;
      const char* Pb = (const char*)Plds;
      const char* Vl = (const char*)Vlds;
#pragma unroll
      for (int ks = 0; ks < 8; ++ks) {
        int sl = ks * 2 + h;
        short8 pf0 = *(const short8*)(Pb + q0 * 256 + ((sl ^ (q0 & 7)) * 16));
        short8 pf1 = *(const short8*)(Pb + q1 * 256 + ((sl ^ (q1 & 7)) * 16));
        short8 vf0 = *(const short8*)(Vl + c0 * 256 + ((sl ^ (c0 & 7)) * 16));
        short8 vf1 = *(const short8*)(Vl + c1 * 256 + ((sl ^ (c1 & 7)) * 16));
        o00 = __builtin_amdgcn_mfma_f32_32x32x16_bf16(vf0, pf0, o00, 0, 0, 0);
        o01 = __builtin_amdgcn_mfma_f32_32x32x16_bf16(vf0, pf1, o01, 0, 0, 0);
        o10 = __builtin_amdgcn_mfma_f32_32x32x16_bf16(vf1, pf0, o10, 0, 0, 0);
        o11 = __builtin_amdgcn_mfma_f32_32x32x16_bf16(vf1, pf1, o11, 0, 0, 0);
      }
    }
    // barrier: K(kt+1) landed; V(kt)/P(kt) fully consumed
    asm volatile("s_waitcnt vmcnt(0) lgkmcnt(0)\ns_barrier" ::: "memory");
  }
#undef STAGE_K
#undef STAGE_V

  // ---- l reconciliation across the 2 m-pair waves per q-slice (Plds -> float[q][2]) ----
  float* lred = (float*)Plds;
  if (lane < 32) lred[(qsl + l32) * 2 + (w & 1)] = l_acc;
  __syncthreads();
  float inv0, inv1;
  {
    const float* lp0 = &lred[(qp + l32) * 2];
    inv0 = 1.f / (lp0[0] + lp0[1]);
    const float* lp1 = &lred[(qp + 32 + l32) * 2];
    inv1 = 1.f / (lp1[0] + lp1[1]);
  }

  // ---- store O^T -> aT[q][c] bf16 ----
  unsigned short* ab = aT + (size_t)b * NPIX * CH;
  const floatx16 oa[2][2] = {{o00, o01}, {o10, o11}};
#pragma unroll
  for (int csub = 0; csub < 2; ++csub)
#pragma unroll
    for (int qsub = 0; qsub < 2; ++qsub) {
      int qg = qbase + qp + qsub * 32 + l32;
      float iv = qsub ? inv1 : inv0;
#pragma unroll
      for (int t = 0; t < 4; ++t) {
        int c = csl + csub * 32 + 8 * t + 4 * h;
        uint2 wv;
        wv.x = pk2bf(oa[csub][qsub][4 * t] * iv, oa[csub][qsub][4 * t + 1] * iv);
        wv.y = pk2bf(oa[csub][qsub][4 * t + 2] * iv, oa[csub][qsub][4 * t + 3] * iv);
        *(uint2*)(ab + (size_t)qg * CH + c) = wv;
      }
    }
}

// ---------------- output projection + bias + residual ----------------
__global__ __launch_bounds__(256, 2) void out_gemm(
    const unsigned short* __restrict__ wob, const unsigned short* __restrict__ aT,
    const float* __restrict__ bo, const float* __restrict__ x, float* __restrict__ outp) {
  int nt = blockIdx.x, ot = blockIdx.y, b = blockIdx.z;
  const unsigned short* A = aT + (size_t)b * NPIX * CH;
  int o0 = ot * 128, n0 = nt * 128;

  __shared__ unsigned short As[128 * 64];
  __shared__ unsigned short Bs[128 * 64];

  int tid = threadIdx.x;
  int wave = tid >> 6, lane = tid & 63, quad = lane >> 4, l16 = lane & 15;
  int wm = (wave >> 1) * 64, wn = (wave & 1) * 64;

  floatx4 acc[4][4];
#pragma unroll
  for (int i = 0; i < 4; ++i)
#pragma unroll
    for (int j = 0; j < 4; ++j) acc[i][j] = (floatx4){0.f, 0.f, 0.f, 0.f};

  for (int k0 = 0; k0 < 256; k0 += 64) {
    __syncthreads();
#pragma unroll
    for (int c2 = 0; c2 < 4; ++c2) {
      int row = wave * 32 + c2 * 8 + (lane >> 3);
      int sc = (lane & 7) ^ (row & 7);
      gload16(wob + (size_t)(o0 + row) * CH + k0 + sc * 8, &As[(wave * 32 + c2 * 8) * 64]);
      gload16(A + (size_t)(n0 + row) * CH + k0 + sc * 8, &Bs[(wave * 32 + c2 * 8) * 64]);
    }
    __syncthreads();
#pragma unroll
    for (int s = 0; s < 2; ++s) {
      short8 af[4], bf[4];
#pragma unroll
      for (int i = 0; i < 4; ++i) {
        int m = wm + i * 16 + l16;
        af[i] = *(const short8*)(As + m * 64 + (((s * 4 + quad) ^ (m & 7)) * 8));
        int n = wn + i * 16 + l16;
        bf[i] = *(const short8*)(Bs + n * 64 + (((s * 4 + quad) ^ (n & 7)) * 8));
      }
#pragma unroll
      for (int i = 0; i < 4; ++i)
#pragma unroll
        for (int j = 0; j < 4; ++j)
          acc[i][j] = __builtin_amdgcn_mfma_f32_16x16x32_bf16(af[i], bf[j], acc[i][j], 0, 0, 0);
    }
  }

#pragma unroll
  for (int i = 0; i < 4; ++i)
#pragma unroll
    for (int r = 0; r < 4; ++r) {
      int o = o0 + wm + i * 16 + quad * 4 + r;
      float bb = bo[o];
#pragma unroll
      for (int j = 0; j < 4; ++j) {
        int n = n0 + wn + j * 16 + l16;
        size_t idx = ((size_t)b * CH + o) * NPIX + n;
        outp[idx] = x[idx] + bb + acc[i][j][r];
      }
    }
}

extern "C" void kernel_launch(void* const* d_in, const int* in_sizes, int n_in,
                              void* d_out, int out_size, void* d_ws, size_t ws_size,
                              hipStream_t stream) {
  const float* x   = (const float*)d_in[0];
  const float* gsc = (const float*)d_in[1];
  const float* gbi = (const float*)d_in[2];
  const float* wq  = (const float*)d_in[3];
  const float* bq  = (const float*)d_in[4];
  const float* wk  = (const float*)d_in[5];
  const float* bk  = (const float*)d_in[6];
  const float* wv  = (const float*)d_in[7];
  const float* bv  = (const float*)d_in[8];
  const float* wo  = (const float*)d_in[9];
  const float* bo  = (const float*)d_in[10];
  float* out = (float*)d_out;

  char* ws = (char*)d_ws;
  unsigned short* xnT  = (unsigned short*)(ws);              // 16 MB (dead after qkv)
  unsigned short* qT   = (unsigned short*)(ws + 16777216);   // 16 MB
  unsigned short* kT   = (unsigned short*)(ws + 33554432);   // 16 MB
  unsigned short* vC   = (unsigned short*)(ws + 50331648);   // 16 MB
  unsigned short* wqkv = (unsigned short*)(ws + 67108864);   // 384 KB
  unsigned short* wob  = (unsigned short*)(ws + 67502080);   // 128 KB
  unsigned short* aT   = (unsigned short*)(ws + 67633152);   // 16 MB

  conv_weights_kernel<<<256, 256, 0, stream>>>(wq, wk, wv, wo, wqkv, wob);
  gn_kernel<<<256, 256, 0, stream>>>(x, gsc, gbi, xnT);
  dim3 g1(32, 2, 24);
  qkv_gemm<<<g1, 256, 0, stream>>>(wqkv, xnT, bq, bk, bv, qT, kT, vC);
  attn_kernel<<<256, 512, 0, stream>>>(qT, kT, vC, aT);
  dim3 g3(32, 2, 8);
  out_gemm<<<g3, 256, 0, stream>>>(wob, aT, bo, x, out);
}